// Round 1
// baseline (126.463 us; speedup 1.0000x reference)
//
#include <hip/hip_runtime.h>

#define EPS_F 1e-6f
#define S_DIM 768
#define W_DIM 32

__global__ __launch_bounds__(256) void cope_fire_kernel(
    const float* __restrict__ attn,   // (H*S, S)
    const float* __restrict__ W_in,   // (32,1)
    const float* __restrict__ b_in,   // (32,)
    const float* __restrict__ W_out,  // (H,32)
    const float* __restrict__ b_out,  // (H,)
    const float* __restrict__ c_p,
    const float* __restrict__ Lm_p,
    const float* __restrict__ iL_p,
    float* __restrict__ out)
{
    const int row = blockIdx.x;        // 0 .. H*S-1
    const int h   = row / S_DIM;
    const int t   = threadIdx.x;
    const int lane = t & 63;
    const int wave = t >> 6;

    __shared__ float s_w1[W_DIM], s_bin[W_DIM], s_wout[W_DIM];
    __shared__ float s_wsum[12];       // 3 segments x 4 waves

    if (t < W_DIM) {
        s_w1[t]   = W_in[t];           // W_in[:,0]
        s_bin[t]  = b_in[t];
        s_wout[t] = W_out[h * W_DIM + t];
    }

    const float* rowp = attn + (size_t)row * S_DIM;
    const float c   = c_p[0];
    const float thr = fabsf(Lm_p[0] * iL_p[0]);
    const float bo  = b_out[h];

    // Load 3 coalesced strided elements; sigmoid.
    float g[3];
#pragma unroll
    for (int s = 0; s < 3; s++) {
        float x = rowp[s * 256 + t];
        g[s] = 1.0f / (1.0f + expf(-x));
    }

    // Per-segment inclusive block scan (wave shuffle scan + wave-sum combine).
    float incl[3];
#pragma unroll
    for (int s = 0; s < 3; s++) {
        float x = g[s];
#pragma unroll
        for (int d = 1; d < 64; d <<= 1) {
            float y = __shfl_up(x, d, 64);
            if (lane >= d) x += y;
        }
        if (lane == 63) s_wsum[s * 4 + wave] = x;
        incl[s] = x;
    }
    __syncthreads();

    float segtot[3];
#pragma unroll
    for (int s = 0; s < 3; s++) {
        float w0 = s_wsum[s * 4 + 0];
        float w1 = s_wsum[s * 4 + 1];
        float w2 = s_wsum[s * 4 + 2];
        float w3 = s_wsum[s * 4 + 3];
        float woff = 0.0f;
        if (wave > 0) woff += w0;
        if (wave > 1) woff += w1;
        if (wave > 2) woff += w2;
        incl[s] += woff;
        segtot[s] = w0 + w1 + w2 + w3;
    }
    // Stitch segments into full-row inclusive prefix.
    const float off1  = segtot[0];
    const float off2  = segtot[0] + segtot[1];
    const float total = off2 + segtot[2];
    incl[1] += off1;
    incl[2] += off2;

    // Row-constant denominator: max_pos == pos[j=0] == total row sum.
    const float den = logf(fabsf(c * fminf(total, thr)) + 1.0f) + EPS_F;
    const float inv_den = 1.0f / den;

    float* outp = out + (size_t)row * S_DIM;
#pragma unroll
    for (int s = 0; s < 3; s++) {
        // suffix sum: pos[j] = total - incl_prefix[j] + g[j]
        float pos  = total - incl[s] + g[s];
        float dist = logf(fabsf(c * pos) + 1.0f) * inv_den;
        float acc = bo;
#pragma unroll
        for (int w = 0; w < W_DIM; w++) {
            float hv = fmaxf(dist * s_w1[w] + s_bin[w], 0.0f);
            acc += hv * s_wout[w];
        }
        outp[s * 256 + t] = acc;
    }
}

extern "C" void kernel_launch(void* const* d_in, const int* in_sizes, int n_in,
                              void* d_out, int out_size, void* d_ws, size_t ws_size,
                              hipStream_t stream) {
    const float* attn  = (const float*)d_in[0];
    const float* W_in  = (const float*)d_in[1];
    const float* b_in  = (const float*)d_in[2];
    const float* W_out = (const float*)d_in[3];
    const float* b_out = (const float*)d_in[4];
    const float* c_p   = (const float*)d_in[5];
    const float* Lm_p  = (const float*)d_in[6];
    const float* iL_p  = (const float*)d_in[7];
    float* out = (float*)d_out;

    const int H = 12;
    const int rows = H * S_DIM;   // 9216 blocks
    cope_fire_kernel<<<rows, 256, 0, stream>>>(
        attn, W_in, b_in, W_out, b_out, c_p, Lm_p, iL_p, out);
}

// Round 2
// 108.270 us; speedup vs baseline: 1.1680x; 1.1680x over previous
//
#include <hip/hip_runtime.h>

#define EPS_F 1e-6f
#define S_DIM 768
#define W_DIM 32

__global__ __launch_bounds__(256, 4) void cope_fire_kernel(
    const float* __restrict__ attn,   // (H*S, S)
    const float* __restrict__ W_in,   // (32,1)
    const float* __restrict__ b_in,   // (32,)
    const float* __restrict__ W_out,  // (H,32)
    const float* __restrict__ b_out,  // (H,)
    const float* __restrict__ c_p,
    const float* __restrict__ Lm_p,
    const float* __restrict__ iL_p,
    float* __restrict__ out)
{
    const int row = blockIdx.x;        // 0 .. H*S-1
    const int h   = row / S_DIM;
    const int t   = threadIdx.x;
    const int lane = t & 63;
    const int wave = t >> 6;

    __shared__ float s_w1[W_DIM], s_bin[W_DIM], s_wout[W_DIM];
    __shared__ float s_wsum[12];       // 3 segments x 4 waves

    if (t < W_DIM) {
        s_w1[t]   = W_in[t];           // W_in[:,0]
        s_bin[t]  = b_in[t];
        s_wout[t] = W_out[h * W_DIM + t];
    }

    const float* rowp = attn + (size_t)row * S_DIM;
    const float c   = c_p[0];
    const float thr = fabsf(Lm_p[0] * iL_p[0]);
    const float bo  = b_out[h];

    // Load 3 coalesced strided elements; sigmoid (fast exp).
    float g[3];
#pragma unroll
    for (int s = 0; s < 3; s++) {
        float x = rowp[s * 256 + t];
        g[s] = 1.0f / (1.0f + __expf(-x));
    }

    // Per-segment inclusive block scan (wave shuffle scan + wave-sum combine).
    float incl[3];
#pragma unroll
    for (int s = 0; s < 3; s++) {
        float x = g[s];
#pragma unroll
        for (int d = 1; d < 64; d <<= 1) {
            float y = __shfl_up(x, d, 64);
            if (lane >= d) x += y;
        }
        if (lane == 63) s_wsum[s * 4 + wave] = x;
        incl[s] = x;
    }
    __syncthreads();

    float segtot[3];
#pragma unroll
    for (int s = 0; s < 3; s++) {
        float w0 = s_wsum[s * 4 + 0];
        float w1 = s_wsum[s * 4 + 1];
        float w2 = s_wsum[s * 4 + 2];
        float w3 = s_wsum[s * 4 + 3];
        float woff = 0.0f;
        if (wave > 0) woff += w0;
        if (wave > 1) woff += w1;
        if (wave > 2) woff += w2;
        incl[s] += woff;
        segtot[s] = w0 + w1 + w2 + w3;
    }
    // Stitch segments into full-row inclusive prefix.
    const float off1  = segtot[0];
    const float off2  = segtot[0] + segtot[1];
    const float total = off2 + segtot[2];
    incl[1] += off1;
    incl[2] += off2;

    // Row-constant denominator: max_pos == pos[j=0] == total row sum.
    const float den = __logf(fabsf(c * fminf(total, thr)) + 1.0f) + EPS_F;
    const float inv_den = 1.0f / den;

    // ---- Pull weights into REGISTERS (fully unrolled, constant indices). ----
    // Fold inv_den into w1 so per-element work is fma -> max -> fma.
    float r_w1[W_DIM], r_bin[W_DIM], r_wout[W_DIM];
#pragma unroll
    for (int w = 0; w < W_DIM; w++) {
        r_w1[w]   = s_w1[w] * inv_den;
        r_bin[w]  = s_bin[w];
        r_wout[w] = s_wout[w];
    }

    float* outp = out + (size_t)row * S_DIM;
#pragma unroll
    for (int s = 0; s < 3; s++) {
        // suffix sum: pos[j] = total - incl_prefix[j] + g[j]
        float pos    = total - incl[s] + g[s];
        float lognum = __logf(fabsf(c * pos) + 1.0f);   // dist = lognum * inv_den (folded)
        float acc = bo;
#pragma unroll
        for (int w = 0; w < W_DIM; w++) {
            float hv = fmaxf(fmaf(lognum, r_w1[w], r_bin[w]), 0.0f);
            acc = fmaf(hv, r_wout[w], acc);
        }
        outp[s * 256 + t] = acc;
    }
}

extern "C" void kernel_launch(void* const* d_in, const int* in_sizes, int n_in,
                              void* d_out, int out_size, void* d_ws, size_t ws_size,
                              hipStream_t stream) {
    const float* attn  = (const float*)d_in[0];
    const float* W_in  = (const float*)d_in[1];
    const float* b_in  = (const float*)d_in[2];
    const float* W_out = (const float*)d_in[3];
    const float* b_out = (const float*)d_in[4];
    const float* c_p   = (const float*)d_in[5];
    const float* Lm_p  = (const float*)d_in[6];
    const float* iL_p  = (const float*)d_in[7];
    float* out = (float*)d_out;

    const int H = 12;
    const int rows = H * S_DIM;   // 9216 blocks
    cope_fire_kernel<<<rows, 256, 0, stream>>>(
        attn, W_in, b_in, W_out, b_out, c_p, Lm_p, iL_p, out);
}